// Round 7
// baseline (2721.597 us; speedup 1.0000x reference)
//
#include <hip/hip_runtime.h>
#include <hip/hip_bf16.h>

#define NN 100000
#define DD 128

// Bucketed aggregation: 64 nodes per bucket
#define NPB2 64
#define NB2 1563                   // ceil(100000/64)
#define CAPB2 1536                 // pairs/bucket (mean 1024, sigma 32 -> +16 sigma)
#define PA_BLOCKS 196              // partA blocks per edge list

typedef unsigned short ushort_t;
typedef unsigned int uint_t;
typedef __attribute__((ext_vector_type(8))) short bf16x8;
typedef __attribute__((ext_vector_type(4))) float f32x4;

__device__ __forceinline__ ushort_t f2bf(float f) {
    uint_t u = __builtin_bit_cast(uint_t, f);
    u += 0x7FFFu + ((u >> 16) & 1u);          // RNE
    return (ushort_t)(u >> 16);
}
__device__ __forceinline__ uint_t pack2bf(float a, float b) {
    return (uint_t)f2bf(a) | ((uint_t)f2bf(b) << 16);
}
__device__ __forceinline__ float bflo(uint_t v) {
    return __builtin_bit_cast(float, v << 16);
}
__device__ __forceinline__ float bfhi(uint_t v) {
    return __builtin_bit_cast(float, v & 0xFFFF0000u);
}

// ---------------------------------------------------------------------------
// Fused prep: feat fp32->bf16 (blocks 0..6249), weight transposes
// (6250..6569), bcnt zeroing (6570..6582).
// ---------------------------------------------------------------------------
#define PREP_FEAT_BLOCKS 6250
#define PREP_W_BLOCKS    320
#define PREP_Z_BLOCKS    13
__global__ __launch_bounds__(256) void prep(
    const float* __restrict__ feat, ushort_t* __restrict__ featb,
    const float* __restrict__ w_proj,
    const float* __restrict__ w_self1, const float* __restrict__ w_neigh1,
    const float* __restrict__ w_self2, const float* __restrict__ w_neigh2,
    ushort_t* __restrict__ wtp, ushort_t* __restrict__ wt1,
    ushort_t* __restrict__ wt2, int* __restrict__ bcnt)
{
    const int bid = blockIdx.x;
    const int tid = threadIdx.x;
    if (bid < PREP_FEAT_BLOCKS) {
        size_t t = (size_t)bid * 256 + tid;
        size_t base = t * 8;
        float4 a = *(const float4*)(feat + base);
        float4 b = *(const float4*)(feat + base + 4);
        uint4 o;
        o.x = pack2bf(a.x, a.y); o.y = pack2bf(a.z, a.w);
        o.z = pack2bf(b.x, b.y); o.w = pack2bf(b.z, b.w);
        *(uint4*)(featb + base) = o;
    } else if (bid < PREP_FEAT_BLOCKS + PREP_W_BLOCKS) {
        int w = bid - PREP_FEAT_BLOCKS;       // 0..319
        int which = w >> 6;                   // 0..4
        int t = (w & 63) * 256 + tid;         // 0..16383
        int n = t >> 7, k = t & 127;
        float v;
        ushort_t* d;
        switch (which) {
            case 0: v = w_proj  [(size_t)k * 128 + n]; d = wtp + (size_t)n * 128 + k;       break;
            case 1: v = w_self1 [(size_t)k * 128 + n]; d = wt1 + (size_t)n * 256 + k;       break;
            case 2: v = w_neigh1[(size_t)k * 128 + n]; d = wt1 + (size_t)n * 256 + 128 + k; break;
            case 3: v = w_self2 [(size_t)k * 128 + n]; d = wt2 + (size_t)n * 256 + k;       break;
            default:v = w_neigh2[(size_t)k * 128 + n]; d = wt2 + (size_t)n * 256 + 128 + k; break;
        }
        *d = f2bf(v);
    } else {
        int i = (bid - PREP_FEAT_BLOCKS - PREP_W_BLOCKS) * 256 + tid;
        if (i < 2 * NB2) bcnt[i] = 0;
    }
}

// ---------------------------------------------------------------------------
// bf16 MFMA GEMM: out = act( [A | Bm] @ W + bias ), W pre-transposed [n][k].
// 128x128 tile/block, 4 waves x (4x4) 16x16x32 MFMA tiles, BK=32.
// Epilogue stages the bf16 output tile in LDS -> coalesced 16B row writes.
// ---------------------------------------------------------------------------
template <bool RELU, bool TWO>
__global__ __launch_bounds__(256, 3) void gemm_bf16(
    const ushort_t* __restrict__ A, const ushort_t* __restrict__ Bm,
    const ushort_t* __restrict__ W, const float* __restrict__ bias,
    ushort_t* __restrict__ outp)
{
    __shared__ ushort_t At[128 * 40];   // 10 KB
    __shared__ ushort_t Wt[128 * 40];   // 10 KB
    __shared__ ushort_t Ot[128 * 128];  // 32 KB output staging

    const int tid  = threadIdx.x;
    const int lane = tid & 63;
    const int wav  = tid >> 6;
    const int row0 = blockIdx.x * 128;
    const int m0   = (wav & 1) * 64;
    const int n0   = (wav >> 1) * 64;
    const int KTOT = TWO ? 256 : 128;
    const int NCH  = TWO ? 8 : 4;

    f32x4 acc[4][4];
#pragma unroll
    for (int i = 0; i < 4; ++i)
#pragma unroll
        for (int j = 0; j < 4; ++j) acc[i][j] = (f32x4){0.f, 0.f, 0.f, 0.f};

    const int cl = lane & 15;
    const int q  = lane >> 4;

#pragma unroll 1
    for (int ch = 0; ch < NCH; ++ch) {
        const ushort_t* __restrict__ sp = (TWO && ch >= 4) ? Bm : A;
        const int kA = (ch & 3) * 32;
        const int kW = ch * 32;

        uint4 av[2], wv[2];
#pragma unroll
        for (int j = 0; j < 2; ++j) {
            int g = tid + 256 * j;
            int r = g >> 2;
            int c = (g & 3) * 8;
            int grow = row0 + r;
            if (grow >= NN) grow = NN - 1;
            av[j] = *(const uint4*)(sp + (size_t)grow * DD + kA + c);
            wv[j] = *(const uint4*)(W + (size_t)r * KTOT + kW + c);
        }
        if (ch) __syncthreads();
#pragma unroll
        for (int j = 0; j < 2; ++j) {
            int g = tid + 256 * j;
            int r = g >> 2;
            int c = (g & 3) * 8;
            *(uint4*)(&At[r * 40 + c]) = av[j];
            *(uint4*)(&Wt[r * 40 + c]) = wv[j];
        }
        __syncthreads();

        bf16x8 af[4], bfr[4];
#pragma unroll
        for (int i = 0; i < 4; ++i)
            af[i] = *(const bf16x8*)(&At[(m0 + i * 16 + cl) * 40 + q * 8]);
#pragma unroll
        for (int j = 0; j < 4; ++j)
            bfr[j] = *(const bf16x8*)(&Wt[(n0 + j * 16 + cl) * 40 + q * 8]);
#pragma unroll
        for (int i = 0; i < 4; ++i)
#pragma unroll
            for (int j = 0; j < 4; ++j)
                acc[i][j] = __builtin_amdgcn_mfma_f32_16x16x32_bf16(
                    af[i], bfr[j], acc[i][j], 0, 0, 0);
    }

    // Epilogue. C/D layout: col=lane&15, row=(lane>>4)*4+reg  [m89/m91]
#pragma unroll
    for (int j = 0; j < 4; ++j) {
        int c = n0 + j * 16 + cl;
        float bv = bias[c];
#pragma unroll
        for (int i = 0; i < 4; ++i) {
#pragma unroll
            for (int reg = 0; reg < 4; ++reg) {
                int r = m0 + i * 16 + 4 * q + reg;
                float v = acc[i][j][reg] + bv;
                if constexpr (RELU) v = fmaxf(v, 0.f);
                Ot[r * 128 + c] = f2bf(v);
            }
        }
    }
    __syncthreads();
    int rows = NN - row0; if (rows > 128) rows = 128;
    for (int t = tid; t < rows * 16; t += 256) {
        int r = t >> 4, c8 = (t & 15) * 8;
        *(uint4*)(outp + (size_t)(row0 + r) * DD + c8) =
            *(const uint4*)(&Ot[r * 128 + c8]);
    }
}

// ---------------------------------------------------------------------------
// partA2: bin BOTH edge lists into 64-node buckets in one launch.
// Pair = (local_dst<<17) | src.  Blocks [0,196) -> list 0, [196,392) -> list 1.
// ---------------------------------------------------------------------------
__global__ __launch_bounds__(256) void partA2(
    const int* __restrict__ e0s, const int* __restrict__ e0d, int E0,
    const int* __restrict__ e1s, const int* __restrict__ e1d, int E1,
    int* __restrict__ bcnt, uint_t* __restrict__ pairs)
{
    __shared__ int hist[NB2];
    __shared__ int base[NB2];
    const int tid  = threadIdx.x;
    const int half = blockIdx.x >= PA_BLOCKS;
    const int* __restrict__ src = half ? e1s : e0s;
    const int* __restrict__ dst = half ? e1d : e0d;
    const int E = half ? E1 : E0;
    int* bc = bcnt + half * NB2;
    uint_t* pp = pairs + (size_t)half * NB2 * CAPB2;
    const int blk = blockIdx.x - half * PA_BLOCKS;
    const int chunk = (E + PA_BLOCKS - 1) / PA_BLOCKS;
    const int ea = blk * chunk;
    int eb = ea + chunk; if (eb > E) eb = E;

    for (int b = tid; b < NB2; b += 256) hist[b] = 0;
    __syncthreads();
    for (int e = ea + tid; e < eb; e += 256)
        atomicAdd(&hist[dst[e] >> 6], 1);
    __syncthreads();
    for (int b = tid; b < NB2; b += 256) {
        base[b] = atomicAdd(&bc[b], hist[b]);
        hist[b] = 0;
    }
    __syncthreads();
    for (int e = ea + tid; e < eb; e += 256) {
        int d = dst[e];
        int b = d >> 6;
        int off = atomicAdd(&hist[b], 1);
        int p = base[b] + off;
        if (p < CAPB2)
            pp[(size_t)b * CAPB2 + p] =
                ((uint_t)(d & (NPB2 - 1)) << 17) | (uint_t)src[e];
    }
}

// ---------------------------------------------------------------------------
// aggB: fused bin->mean. One block per 64-node bucket; 4 waves split the
// pair list; 8-deep unrolled row gathers (64 lanes x dword = 256 B row);
// LDS fp32 atomic accumulation (2-way bank aliasing = free); mean out bf16.
// ---------------------------------------------------------------------------
__global__ __launch_bounds__(256, 4) void aggB(
    const ushort_t* __restrict__ h, const uint_t* __restrict__ pairs,
    const int* __restrict__ bcnt, ushort_t* __restrict__ mean)
{
    __shared__ float acc[NPB2 * DD];   // 32 KB
    __shared__ int   cnt[NPB2];

    const int tid = threadIdx.x;
    const int b   = blockIdx.x;
    const int n0  = b * NPB2;
    int tot = bcnt[b]; if (tot > CAPB2) tot = CAPB2;
    const uint_t* pb = pairs + (size_t)b * CAPB2;

    for (int i = tid; i < NPB2 * DD / 4; i += 256)
        ((float4*)acc)[i] = make_float4(0.f, 0.f, 0.f, 0.f);
    if (tid < NPB2) cnt[tid] = 0;
    __syncthreads();

    const int lane = tid & 63;
    const int wav  = tid >> 6;
    const int per  = (tot + 3) >> 2;
    const int i0   = wav * per;
    int i1 = i0 + per; if (i1 > tot) i1 = tot;

    int i = i0;
    for (; i + 8 <= i1; i += 8) {
        uint_t p[8], v[8];
#pragma unroll
        for (int j = 0; j < 8; ++j) p[j] = pb[i + j];
#pragma unroll
        for (int j = 0; j < 8; ++j)
            v[j] = *(const uint_t*)(h + (size_t)(p[j] & 0x1FFFFu) * DD + lane * 2);
#pragma unroll
        for (int j = 0; j < 8; ++j) {
            int ldst = p[j] >> 17;
            if (lane == 0) atomicAdd(&cnt[ldst], 1);
            float* ap = &acc[ldst * DD + lane * 2];
            atomicAdd(ap,     bflo(v[j]));
            atomicAdd(ap + 1, bfhi(v[j]));
        }
    }
    for (; i < i1; ++i) {
        uint_t p = pb[i];
        uint_t v = *(const uint_t*)(h + (size_t)(p & 0x1FFFFu) * DD + lane * 2);
        int ldst = p >> 17;
        if (lane == 0) atomicAdd(&cnt[ldst], 1);
        float* ap = &acc[ldst * DD + lane * 2];
        atomicAdd(ap,     bflo(v));
        atomicAdd(ap + 1, bfhi(v));
    }
    __syncthreads();

    int nmax = NN - n0; if (nmax > NPB2) nmax = NPB2;
    for (int idx = tid; idx < NPB2 * 64; idx += 256) {
        int node = idx >> 6;
        int c2   = idx & 63;
        if (node < nmax) {
            int c = cnt[node];
            float rinv = 1.0f / (float)(c > 1 ? c : 1);
            float lo = acc[node * DD + 2 * c2]     * rinv;
            float hi = acc[node * DD + 2 * c2 + 1] * rinv;
            *(uint_t*)(mean + (size_t)(n0 + node) * DD + 2 * c2) = pack2bf(lo, hi);
        }
    }
}

// ---------------------------------------------------------------------------
// Fused edge scoring on bf16 h3: 16 lanes/edge, uint4 (16 B) loads.
// ---------------------------------------------------------------------------
__global__ __launch_bounds__(256) void score_both(
    const ushort_t* __restrict__ h,
    const int* __restrict__ ps, const int* __restrict__ pd,
    const int* __restrict__ ns, const int* __restrict__ nd,
    float* __restrict__ out, int EP, int TE)
{
    int gid = blockIdx.x * 256 + threadIdx.x;
    int e = gid >> 4;
    if (e >= TE) return;
    int lane = gid & 15;
    int si, di;
    if (e < EP) { si = ps[e]; di = pd[e]; }
    else        { si = ns[e - EP]; di = nd[e - EP]; }
    uint4 a = *(const uint4*)(h + (size_t)si * DD + lane * 8);
    uint4 b = *(const uint4*)(h + (size_t)di * DD + lane * 8);
    float s = bflo(a.x) * bflo(b.x) + bfhi(a.x) * bfhi(b.x)
            + bflo(a.y) * bflo(b.y) + bfhi(a.y) * bfhi(b.y)
            + bflo(a.z) * bflo(b.z) + bfhi(a.z) * bfhi(b.z)
            + bflo(a.w) * bflo(b.w) + bfhi(a.w) * bfhi(b.w);
#pragma unroll
    for (int off = 8; off; off >>= 1) s += __shfl_down(s, off, 16);
    if (lane == 0) out[e] = s;
}

// ---------------------------------------------------------------------------

extern "C" void kernel_launch(void* const* d_in, const int* in_sizes, int n_in,
                              void* d_out, int out_size, void* d_ws, size_t ws_size,
                              hipStream_t stream)
{
    const float* feat    = (const float*)d_in[0];
    const int*   e0s     = (const int*)d_in[1];
    const int*   e0d     = (const int*)d_in[2];
    const int*   e1s     = (const int*)d_in[3];
    const int*   e1d     = (const int*)d_in[4];
    const int*   ps      = (const int*)d_in[5];
    const int*   pd      = (const int*)d_in[6];
    const int*   ns      = (const int*)d_in[7];
    const int*   nd      = (const int*)d_in[8];
    const float* w_proj  = (const float*)d_in[9];
    const float* b_proj  = (const float*)d_in[10];
    const float* w_self1 = (const float*)d_in[11];
    const float* w_neigh1= (const float*)d_in[12];
    const float* b1      = (const float*)d_in[13];
    const float* w_self2 = (const float*)d_in[14];
    const float* w_neigh2= (const float*)d_in[15];
    const float* b2      = (const float*)d_in[16];

    float* out = (float*)d_out;

    const size_t NF = (size_t)NN * DD;
    char* base = (char*)d_ws;

    // bf16 buffers, NF*2 bytes each. featb dies after layer-0 gemm; h3
    // reuses its slot.
    ushort_t* featb = (ushort_t*)base;
    ushort_t* h3    = (ushort_t*)base;
    ushort_t* h1    = (ushort_t*)(base + NF * 2);
    ushort_t* mean  = (ushort_t*)(base + NF * 4);
    ushort_t* h2    = (ushort_t*)(base + NF * 6);

    uint_t* pairs = (uint_t*)(base + NF * 8);          // 2*NB2*CAPB2*4 = 19.2 MB
    int*    bcnt  = (int*)(pairs + (size_t)2 * NB2 * CAPB2);   // [2*NB2]
    ushort_t* wts = (ushort_t*)(bcnt + 2 * NB2);
    ushort_t* wtp = wts;                 // [128][128]
    ushort_t* wt1 = wts + 128 * 128;     // [128][256]
    ushort_t* wt2 = wt1 + 128 * 256;     // [128][256]

    const int E0 = in_sizes[1];
    const int E1 = in_sizes[3];
    const int EP = in_sizes[5];
    const int EN = in_sizes[7];

    const int GB = (NN + 127) / 128;     // 782

    // ---- Prep (one launch): feat->bf16, weight transposes, bcnt zero
    prep<<<PREP_FEAT_BLOCKS + PREP_W_BLOCKS + PREP_Z_BLOCKS, 256, 0, stream>>>(
        feat, featb, w_proj, w_self1, w_neigh1, w_self2, w_neigh2,
        wtp, wt1, wt2, bcnt);

    // ---- Bin both edge lists (one launch)
    partA2<<<2 * PA_BLOCKS, 256, 0, stream>>>(
        e0s, e0d, E0, e1s, e1d, E1, bcnt, pairs);

    // ---- Layer 0: h1 = relu(feat @ w_proj + b_proj)
    gemm_bf16<true, false><<<GB, 256, 0, stream>>>(
        featb, nullptr, wtp, b_proj, h1);

    // ---- Layer 1: mean over edge0, then dual GEMM
    aggB<<<NB2, 256, 0, stream>>>(h1, pairs, bcnt, mean);
    gemm_bf16<true, true><<<GB, 256, 0, stream>>>(
        h1, mean, wt1, b1, h2);

    // ---- Layer 2: mean over edge1, then dual GEMM (h3 overwrites featb slot)
    aggB<<<NB2, 256, 0, stream>>>(h2, pairs + (size_t)NB2 * CAPB2, bcnt + NB2, mean);
    gemm_bf16<false, true><<<GB, 256, 0, stream>>>(
        h2, mean, wt2, b2, h3);

    // ---- Fused scoring on bf16 h3
    const int TE = EP + EN;
    score_both<<<(TE * 16 + 255) / 256, 256, 0, stream>>>(
        h3, ps, pd, ns, nd, out, EP, TE);
}

// Round 8
// 484.417 us; speedup vs baseline: 5.6183x; 5.6183x over previous
//
#include <hip/hip_runtime.h>
#include <hip/hip_bf16.h>

#define NN 100000
#define DD 128

// Bucketed CSR build: 512 nodes per bucket
#define NPB 512
#define NB 196                     // ceil(100000/512)
#define CAPB 12288                 // pairs/bucket (mean 8192, huge slack)
#define PA_BLOCKS 196              // partA blocks per edge list

typedef unsigned short ushort_t;
typedef unsigned int uint_t;
typedef __attribute__((ext_vector_type(8))) short bf16x8;
typedef __attribute__((ext_vector_type(4))) float f32x4;

__device__ __forceinline__ ushort_t f2bf(float f) {
    uint_t u = __builtin_bit_cast(uint_t, f);
    u += 0x7FFFu + ((u >> 16) & 1u);          // RNE
    return (ushort_t)(u >> 16);
}
__device__ __forceinline__ uint_t pack2bf(float a, float b) {
    return (uint_t)f2bf(a) | ((uint_t)f2bf(b) << 16);
}
__device__ __forceinline__ float bflo(uint_t v) {
    return __builtin_bit_cast(float, v << 16);
}
__device__ __forceinline__ float bfhi(uint_t v) {
    return __builtin_bit_cast(float, v & 0xFFFF0000u);
}

// ---------------------------------------------------------------------------
// Fused prep: feat fp32->bf16, weight transposes, bcnt zeroing. One launch.
// ---------------------------------------------------------------------------
#define PREP_FEAT_BLOCKS 6250
#define PREP_W_BLOCKS    320
#define PREP_Z_BLOCKS    2
__global__ __launch_bounds__(256) void prep(
    const float* __restrict__ feat, ushort_t* __restrict__ featb,
    const float* __restrict__ w_proj,
    const float* __restrict__ w_self1, const float* __restrict__ w_neigh1,
    const float* __restrict__ w_self2, const float* __restrict__ w_neigh2,
    ushort_t* __restrict__ wtp, ushort_t* __restrict__ wt1,
    ushort_t* __restrict__ wt2, int* __restrict__ bcnt)
{
    const int bid = blockIdx.x;
    const int tid = threadIdx.x;
    if (bid < PREP_FEAT_BLOCKS) {
        size_t t = (size_t)bid * 256 + tid;
        size_t base = t * 8;
        float4 a = *(const float4*)(feat + base);
        float4 b = *(const float4*)(feat + base + 4);
        uint4 o;
        o.x = pack2bf(a.x, a.y); o.y = pack2bf(a.z, a.w);
        o.z = pack2bf(b.x, b.y); o.w = pack2bf(b.z, b.w);
        *(uint4*)(featb + base) = o;
    } else if (bid < PREP_FEAT_BLOCKS + PREP_W_BLOCKS) {
        int w = bid - PREP_FEAT_BLOCKS;       // 0..319
        int which = w >> 6;                   // 0..4
        int t = (w & 63) * 256 + tid;         // 0..16383
        int n = t >> 7, k = t & 127;
        float v;
        ushort_t* d;
        switch (which) {
            case 0: v = w_proj  [(size_t)k * 128 + n]; d = wtp + (size_t)n * 128 + k;       break;
            case 1: v = w_self1 [(size_t)k * 128 + n]; d = wt1 + (size_t)n * 256 + k;       break;
            case 2: v = w_neigh1[(size_t)k * 128 + n]; d = wt1 + (size_t)n * 256 + 128 + k; break;
            case 3: v = w_self2 [(size_t)k * 128 + n]; d = wt2 + (size_t)n * 256 + k;       break;
            default:v = w_neigh2[(size_t)k * 128 + n]; d = wt2 + (size_t)n * 256 + 128 + k; break;
        }
        *d = f2bf(v);
    } else {
        int i = (bid - PREP_FEAT_BLOCKS - PREP_W_BLOCKS) * 256 + tid;
        if (i < 2 * NB) bcnt[i] = 0;
    }
}

// ---------------------------------------------------------------------------
// bf16 MFMA GEMM: out = act( [A | Bm] @ W + bias ), W pre-transposed [n][k].
// 128x128 tile/block, 4 waves x (4x4) 16x16x32 MFMA tiles, BK=32.
// Epilogue stages the bf16 output tile in LDS -> coalesced 16B row writes.
// ---------------------------------------------------------------------------
template <bool RELU, bool TWO>
__global__ __launch_bounds__(256, 3) void gemm_bf16(
    const ushort_t* __restrict__ A, const ushort_t* __restrict__ Bm,
    const ushort_t* __restrict__ W, const float* __restrict__ bias,
    ushort_t* __restrict__ outp)
{
    __shared__ ushort_t At[128 * 40];   // 10 KB
    __shared__ ushort_t Wt[128 * 40];   // 10 KB
    __shared__ ushort_t Ot[128 * 128];  // 32 KB output staging

    const int tid  = threadIdx.x;
    const int lane = tid & 63;
    const int wav  = tid >> 6;
    const int row0 = blockIdx.x * 128;
    const int m0   = (wav & 1) * 64;
    const int n0   = (wav >> 1) * 64;
    const int KTOT = TWO ? 256 : 128;
    const int NCH  = TWO ? 8 : 4;

    f32x4 acc[4][4];
#pragma unroll
    for (int i = 0; i < 4; ++i)
#pragma unroll
        for (int j = 0; j < 4; ++j) acc[i][j] = (f32x4){0.f, 0.f, 0.f, 0.f};

    const int cl = lane & 15;
    const int q  = lane >> 4;

#pragma unroll 1
    for (int ch = 0; ch < NCH; ++ch) {
        const ushort_t* __restrict__ sp = (TWO && ch >= 4) ? Bm : A;
        const int kA = (ch & 3) * 32;
        const int kW = ch * 32;

        uint4 av[2], wv[2];
#pragma unroll
        for (int j = 0; j < 2; ++j) {
            int g = tid + 256 * j;
            int r = g >> 2;
            int c = (g & 3) * 8;
            int grow = row0 + r;
            if (grow >= NN) grow = NN - 1;
            av[j] = *(const uint4*)(sp + (size_t)grow * DD + kA + c);
            wv[j] = *(const uint4*)(W + (size_t)r * KTOT + kW + c);
        }
        if (ch) __syncthreads();
#pragma unroll
        for (int j = 0; j < 2; ++j) {
            int g = tid + 256 * j;
            int r = g >> 2;
            int c = (g & 3) * 8;
            *(uint4*)(&At[r * 40 + c]) = av[j];
            *(uint4*)(&Wt[r * 40 + c]) = wv[j];
        }
        __syncthreads();

        bf16x8 af[4], bfr[4];
#pragma unroll
        for (int i = 0; i < 4; ++i)
            af[i] = *(const bf16x8*)(&At[(m0 + i * 16 + cl) * 40 + q * 8]);
#pragma unroll
        for (int j = 0; j < 4; ++j)
            bfr[j] = *(const bf16x8*)(&Wt[(n0 + j * 16 + cl) * 40 + q * 8]);
#pragma unroll
        for (int i = 0; i < 4; ++i)
#pragma unroll
            for (int j = 0; j < 4; ++j)
                acc[i][j] = __builtin_amdgcn_mfma_f32_16x16x32_bf16(
                    af[i], bfr[j], acc[i][j], 0, 0, 0);
    }

    // Epilogue. C/D layout: col=lane&15, row=(lane>>4)*4+reg  [m89/m91]
#pragma unroll
    for (int j = 0; j < 4; ++j) {
        int c = n0 + j * 16 + cl;
        float bv = bias[c];
#pragma unroll
        for (int i = 0; i < 4; ++i) {
#pragma unroll
            for (int reg = 0; reg < 4; ++reg) {
                int r = m0 + i * 16 + 4 * q + reg;
                float v = acc[i][j][reg] + bv;
                if constexpr (RELU) v = fmaxf(v, 0.f);
                Ot[r * 128 + c] = f2bf(v);
            }
        }
    }
    __syncthreads();
    int rows = NN - row0; if (rows > 128) rows = 128;
    for (int t = tid; t < rows * 16; t += 256) {
        int r = t >> 4, c8 = (t & 15) * 8;
        *(uint4*)(outp + (size_t)(row0 + r) * DD + c8) =
            *(const uint4*)(&Ot[r * 128 + c8]);
    }
}

// ---------------------------------------------------------------------------
// partA2: bin BOTH edge lists into 512-node buckets in one launch.
// Pair = (local_dst<<17) | src.  Blocks [0,196)->list 0, [196,392)->list 1.
// ---------------------------------------------------------------------------
__global__ __launch_bounds__(256) void partA2(
    const int* __restrict__ e0s, const int* __restrict__ e0d, int E0,
    const int* __restrict__ e1s, const int* __restrict__ e1d, int E1,
    int* __restrict__ bcnt, uint_t* __restrict__ pairs)
{
    __shared__ int hist[NB];
    __shared__ int base[NB];
    const int tid  = threadIdx.x;
    const int half = blockIdx.x >= PA_BLOCKS;
    const int* __restrict__ src = half ? e1s : e0s;
    const int* __restrict__ dst = half ? e1d : e0d;
    const int E = half ? E1 : E0;
    int* bc = bcnt + half * NB;
    uint_t* pp = pairs + (size_t)half * NB * CAPB;
    const int blk = blockIdx.x - half * PA_BLOCKS;
    const int chunk = (E + PA_BLOCKS - 1) / PA_BLOCKS;
    const int ea = blk * chunk;
    int eb = ea + chunk; if (eb > E) eb = E;

    for (int b = tid; b < NB; b += 256) hist[b] = 0;
    __syncthreads();
    for (int e = ea + tid; e < eb; e += 256)
        atomicAdd(&hist[dst[e] >> 9], 1);
    __syncthreads();
    for (int b = tid; b < NB; b += 256) {
        base[b] = atomicAdd(&bc[b], hist[b]);
        hist[b] = 0;
    }
    __syncthreads();
    for (int e = ea + tid; e < eb; e += 256) {
        int d = dst[e];
        int b = d >> 9;
        int off = atomicAdd(&hist[b], 1);
        int p = base[b] + off;
        if (p < CAPB)
            pp[(size_t)b * CAPB + p] =
                ((uint_t)(d & (NPB - 1)) << 17) | (uint_t)src[e];
    }
}

// ---------------------------------------------------------------------------
// partB: one block per bucket (both lists, 392 blocks). Sort the bucket's
// pairs by local dst in LDS, write the src list back IN PLACE into the
// pairs buffer (coalesced), emit counts[] and offs[] (offs = global index
// into the pairs buffer).
// ---------------------------------------------------------------------------
__global__ __launch_bounds__(256, 2) void partB(
    uint_t* __restrict__ pairs, const int* __restrict__ bcnt,
    int* __restrict__ counts, int* __restrict__ offs)
{
    __shared__ int cnt[NPB];
    __shared__ int loff[NPB];
    __shared__ int ssc[256];
    __shared__ int image[CAPB];

    const int tid  = threadIdx.x;
    const int half = blockIdx.x >= NB;
    const int b    = blockIdx.x - half * NB;
    const int n0   = b << 9;
    int nb = NN - n0; if (nb > NPB) nb = NPB;
    int tot = bcnt[half * NB + b]; if (tot > CAPB) tot = CAPB;
    uint_t* pb = pairs + (size_t)(half * NB + b) * CAPB;
    const int gbase = (half * NB + b) * CAPB;
    int* cnts  = counts + (size_t)half * NN;
    int* offsl = offs   + (size_t)half * NN;

    for (int n = tid; n < NPB; n += 256) cnt[n] = 0;
    __syncthreads();
    for (int i = tid; i < tot; i += 256)
        atomicAdd(&cnt[pb[i] >> 17], 1);
    __syncthreads();

    // exclusive scan of cnt[0..511] with 256 threads
    int a0 = cnt[2 * tid], a1 = cnt[2 * tid + 1];
    int s = a0 + a1;
    ssc[tid] = s;
    __syncthreads();
    for (int off = 1; off < 256; off <<= 1) {
        int t = 0;
        if (tid >= off) t = ssc[tid - off];
        __syncthreads();
        if (tid >= off) ssc[tid] += t;
        __syncthreads();
    }
    int pre = ssc[tid] - s;
    loff[2 * tid]     = pre;
    loff[2 * tid + 1] = pre + a0;
    __syncthreads();

    for (int n = tid; n < nb; n += 256) {
        cnts[n0 + n]  = cnt[n];
        offsl[n0 + n] = gbase + loff[n];
    }
    for (int n = tid; n < NPB; n += 256) cnt[n] = 0;   // reuse as cursor
    __syncthreads();

    for (int i = tid; i < tot; i += 256) {
        uint_t p = pb[i];
        int ln  = p >> 17;
        int pos = loff[ln] + atomicAdd(&cnt[ln], 1);
        image[pos] = (int)(p & 0x1FFFFu);
    }
    __syncthreads();
    for (int i = tid; i < tot; i += 256) pb[i] = (uint_t)image[i];
}

// ---------------------------------------------------------------------------
// CSR mean-aggregate over bf16 h (register accumulation, no atomics).
// 32 lanes/node, uint2 (8 B)/lane, 8-deep unrolled gathers.
// csr = the pairs buffer after partB (plain src ints); offs indexes into it.
// ---------------------------------------------------------------------------
__global__ __launch_bounds__(256) void aggregate_bf16(
    const ushort_t* __restrict__ h, const uint_t* __restrict__ csr,
    const int* __restrict__ offs, const int* __restrict__ counts,
    ushort_t* __restrict__ mean, int nn)
{
    int gid  = blockIdx.x * 256 + threadIdx.x;
    int node = gid >> 5;
    if (node >= nn) return;
    int lane  = gid & 31;
    int start = offs[node];
    int cnt   = counts[node];

    float a0 = 0.f, a1 = 0.f, a2 = 0.f, a3 = 0.f;
    int j = 0;
    for (; j + 8 <= cnt; j += 8) {
        int s[8];
#pragma unroll
        for (int u = 0; u < 8; ++u) s[u] = (int)csr[start + j + u];
        uint2 v[8];
#pragma unroll
        for (int u = 0; u < 8; ++u)
            v[u] = *(const uint2*)(h + (size_t)s[u] * DD + lane * 4);
#pragma unroll
        for (int u = 0; u < 8; ++u) {
            a0 += bflo(v[u].x); a1 += bfhi(v[u].x);
            a2 += bflo(v[u].y); a3 += bfhi(v[u].y);
        }
    }
    for (; j < cnt; ++j) {
        int s = (int)csr[start + j];
        uint2 v = *(const uint2*)(h + (size_t)s * DD + lane * 4);
        a0 += bflo(v.x); a1 += bfhi(v.x);
        a2 += bflo(v.y); a3 += bfhi(v.y);
    }
    float rinv = 1.0f / (float)(cnt > 1 ? cnt : 1);
    uint2 o;
    o.x = pack2bf(a0 * rinv, a1 * rinv);
    o.y = pack2bf(a2 * rinv, a3 * rinv);
    *(uint2*)(mean + (size_t)node * DD + lane * 4) = o;
}

// ---------------------------------------------------------------------------
// Fused edge scoring on bf16 h3: 16 lanes/edge, uint4 (16 B) loads.
// ---------------------------------------------------------------------------
__global__ __launch_bounds__(256) void score_both(
    const ushort_t* __restrict__ h,
    const int* __restrict__ ps, const int* __restrict__ pd,
    const int* __restrict__ ns, const int* __restrict__ nd,
    float* __restrict__ out, int EP, int TE)
{
    int gid = blockIdx.x * 256 + threadIdx.x;
    int e = gid >> 4;
    if (e >= TE) return;
    int lane = gid & 15;
    int si, di;
    if (e < EP) { si = ps[e]; di = pd[e]; }
    else        { si = ns[e - EP]; di = nd[e - EP]; }
    uint4 a = *(const uint4*)(h + (size_t)si * DD + lane * 8);
    uint4 b = *(const uint4*)(h + (size_t)di * DD + lane * 8);
    float s = bflo(a.x) * bflo(b.x) + bfhi(a.x) * bfhi(b.x)
            + bflo(a.y) * bflo(b.y) + bfhi(a.y) * bfhi(b.y)
            + bflo(a.z) * bflo(b.z) + bfhi(a.z) * bfhi(b.z)
            + bflo(a.w) * bflo(b.w) + bfhi(a.w) * bfhi(b.w);
#pragma unroll
    for (int off = 8; off; off >>= 1) s += __shfl_down(s, off, 16);
    if (lane == 0) out[e] = s;
}

// ---------------------------------------------------------------------------

extern "C" void kernel_launch(void* const* d_in, const int* in_sizes, int n_in,
                              void* d_out, int out_size, void* d_ws, size_t ws_size,
                              hipStream_t stream)
{
    const float* feat    = (const float*)d_in[0];
    const int*   e0s     = (const int*)d_in[1];
    const int*   e0d     = (const int*)d_in[2];
    const int*   e1s     = (const int*)d_in[3];
    const int*   e1d     = (const int*)d_in[4];
    const int*   ps      = (const int*)d_in[5];
    const int*   pd      = (const int*)d_in[6];
    const int*   ns      = (const int*)d_in[7];
    const int*   nd      = (const int*)d_in[8];
    const float* w_proj  = (const float*)d_in[9];
    const float* b_proj  = (const float*)d_in[10];
    const float* w_self1 = (const float*)d_in[11];
    const float* w_neigh1= (const float*)d_in[12];
    const float* b1      = (const float*)d_in[13];
    const float* w_self2 = (const float*)d_in[14];
    const float* w_neigh2= (const float*)d_in[15];
    const float* b2      = (const float*)d_in[16];

    float* out = (float*)d_out;

    const size_t NF = (size_t)NN * DD;
    char* base = (char*)d_ws;

    // bf16 buffers, NF*2 bytes each. featb dies after layer-0 gemm; h3
    // reuses its slot.
    ushort_t* featb = (ushort_t*)base;
    ushort_t* h3    = (ushort_t*)base;
    ushort_t* h1    = (ushort_t*)(base + NF * 2);
    ushort_t* mean  = (ushort_t*)(base + NF * 4);
    ushort_t* h2    = (ushort_t*)(base + NF * 6);

    uint_t* pairs  = (uint_t*)(base + NF * 8);           // 2*NB*CAPB*4 = 19.3 MB
    int*    bcnt   = (int*)(pairs + (size_t)2 * NB * CAPB);   // [2*NB]
    int*    counts = bcnt + 2 * NB;                      // [2*NN]
    int*    offs   = counts + 2 * NN;                    // [2*NN]
    ushort_t* wts  = (ushort_t*)(offs + 2 * NN);
    ushort_t* wtp = wts;                 // [128][128]
    ushort_t* wt1 = wts + 128 * 128;     // [128][256]
    ushort_t* wt2 = wt1 + 128 * 256;     // [128][256]

    const int E0 = in_sizes[1];
    const int E1 = in_sizes[3];
    const int EP = in_sizes[5];
    const int EN = in_sizes[7];

    const int GB = (NN + 127) / 128;     // 782
    const int AGB = (NN * 32 + 255) / 256;

    // ---- Prep (one launch): feat->bf16, weight transposes, bcnt zero
    prep<<<PREP_FEAT_BLOCKS + PREP_W_BLOCKS + PREP_Z_BLOCKS, 256, 0, stream>>>(
        feat, featb, w_proj, w_self1, w_neigh1, w_self2, w_neigh2,
        wtp, wt1, wt2, bcnt);

    // ---- Build both CSRs up front (2 launches)
    partA2<<<2 * PA_BLOCKS, 256, 0, stream>>>(
        e0s, e0d, E0, e1s, e1d, E1, bcnt, pairs);
    partB<<<2 * NB, 256, 0, stream>>>(pairs, bcnt, counts, offs);

    // ---- Layer 0: h1 = relu(feat @ w_proj + b_proj)
    gemm_bf16<true, false><<<GB, 256, 0, stream>>>(
        featb, nullptr, wtp, b_proj, h1);

    // ---- Layer 1: mean over edge0, then dual GEMM
    aggregate_bf16<<<AGB, 256, 0, stream>>>(h1, pairs, offs, counts, mean, NN);
    gemm_bf16<true, true><<<GB, 256, 0, stream>>>(
        h1, mean, wt1, b1, h2);

    // ---- Layer 2: mean over edge1, then dual GEMM (h3 overwrites featb slot)
    aggregate_bf16<<<AGB, 256, 0, stream>>>(
        h2, pairs, offs + NN, counts + NN, mean, NN);
    gemm_bf16<false, true><<<GB, 256, 0, stream>>>(
        h2, mean, wt2, b2, h3);

    // ---- Fused scoring on bf16 h3
    const int TE = EP + EN;
    score_both<<<(TE * 16 + 255) / 256, 256, 0, stream>>>(
        h3, ps, pd, ns, nd, out, EP, TE);
}

// Round 9
// 478.608 us; speedup vs baseline: 5.6865x; 1.0121x over previous
//
#include <hip/hip_runtime.h>
#include <hip/hip_bf16.h>

#define NN 100000
#define DD 128

// Bucketed CSR build: 512 nodes per bucket
#define NPB 512
#define NB 196                     // ceil(100000/512)
#define CAPB 12288                 // pairs/bucket (mean 8192, huge slack)
#define PA_BLOCKS 196              // partA blocks per edge list

typedef unsigned short ushort_t;
typedef unsigned int uint_t;
typedef __attribute__((ext_vector_type(8))) short bf16x8;
typedef __attribute__((ext_vector_type(4))) float f32x4;

__device__ __forceinline__ ushort_t f2bf(float f) {
    uint_t u = __builtin_bit_cast(uint_t, f);
    u += 0x7FFFu + ((u >> 16) & 1u);          // RNE
    return (ushort_t)(u >> 16);
}
__device__ __forceinline__ uint_t pack2bf(float a, float b) {
    return (uint_t)f2bf(a) | ((uint_t)f2bf(b) << 16);
}
__device__ __forceinline__ float bflo(uint_t v) {
    return __builtin_bit_cast(float, v << 16);
}
__device__ __forceinline__ float bfhi(uint_t v) {
    return __builtin_bit_cast(float, v & 0xFFFF0000u);
}

// ---------------------------------------------------------------------------
// prep: weight transposes (blocks 0..319) + bcnt zeroing (320..321).
// feat conversion is fused into gemm0 (CVT path).
// ---------------------------------------------------------------------------
#define PREP_W_BLOCKS 320
#define PREP_Z_BLOCKS 2
__global__ __launch_bounds__(256) void prep(
    const float* __restrict__ w_proj,
    const float* __restrict__ w_self1, const float* __restrict__ w_neigh1,
    const float* __restrict__ w_self2, const float* __restrict__ w_neigh2,
    ushort_t* __restrict__ wtp, ushort_t* __restrict__ wt1,
    ushort_t* __restrict__ wt2, int* __restrict__ bcnt)
{
    const int bid = blockIdx.x;
    const int tid = threadIdx.x;
    if (bid < PREP_W_BLOCKS) {
        int which = bid >> 6;                 // 0..4
        int t = (bid & 63) * 256 + tid;       // 0..16383
        int n = t >> 7, k = t & 127;
        float v;
        ushort_t* d;
        switch (which) {
            case 0: v = w_proj  [(size_t)k * 128 + n]; d = wtp + (size_t)n * 128 + k;       break;
            case 1: v = w_self1 [(size_t)k * 128 + n]; d = wt1 + (size_t)n * 256 + k;       break;
            case 2: v = w_neigh1[(size_t)k * 128 + n]; d = wt1 + (size_t)n * 256 + 128 + k; break;
            case 3: v = w_self2 [(size_t)k * 128 + n]; d = wt2 + (size_t)n * 256 + k;       break;
            default:v = w_neigh2[(size_t)k * 128 + n]; d = wt2 + (size_t)n * 256 + 128 + k; break;
        }
        *d = f2bf(v);
    } else {
        int i = (bid - PREP_W_BLOCKS) * 256 + tid;
        if (i < 2 * NB) bcnt[i] = 0;
    }
}

// ---------------------------------------------------------------------------
// bf16 MFMA GEMM: out = act( [A | Bm] @ W + bias ), W pre-transposed [n][k].
// 128x128 tile/block, 4 waves x (4x4) 16x16x32 MFMA tiles, BK=32.
// CVT: A is fp32, converted to bf16 in-register during staging (layer 0).
// LDS: At+Wt (20 KB) unioned with epilogue Ot (32 KB) -> 32 KB total,
// 4-5 blocks/CU (was 3 at 52 KB).
// ---------------------------------------------------------------------------
template <bool RELU, bool TWO, bool CVT>
__global__ __launch_bounds__(256, 4) void gemm_bf16(
    const void* __restrict__ Av, const ushort_t* __restrict__ Bm,
    const ushort_t* __restrict__ W, const float* __restrict__ bias,
    ushort_t* __restrict__ outp)
{
    __shared__ char smem[32768];
    ushort_t* At = (ushort_t*)smem;             // 128*40*2 = 10240 B
    ushort_t* Wt = (ushort_t*)(smem + 10240);   // 10240 B
    ushort_t* Ot = (ushort_t*)smem;             // epilogue: full 32 KB

    const int tid  = threadIdx.x;
    const int lane = tid & 63;
    const int wav  = tid >> 6;
    const int row0 = blockIdx.x * 128;
    const int m0   = (wav & 1) * 64;
    const int n0   = (wav >> 1) * 64;
    const int KTOT = TWO ? 256 : 128;
    const int NCH  = TWO ? 8 : 4;

    f32x4 acc[4][4];
#pragma unroll
    for (int i = 0; i < 4; ++i)
#pragma unroll
        for (int j = 0; j < 4; ++j) acc[i][j] = (f32x4){0.f, 0.f, 0.f, 0.f};

    const int cl = lane & 15;
    const int q  = lane >> 4;

#pragma unroll 1
    for (int ch = 0; ch < NCH; ++ch) {
        const bool second = TWO && (ch >= 4);
        const int kA = (ch & 3) * 32;
        const int kW = ch * 32;

        uint4 av[2], wv[2];
#pragma unroll
        for (int j = 0; j < 2; ++j) {
            int g = tid + 256 * j;
            int r = g >> 2;
            int c = (g & 3) * 8;
            int grow = row0 + r;
            if (grow >= NN) grow = NN - 1;
            if constexpr (CVT) {
                const float* fp = (const float*)Av;
                float4 f0 = *(const float4*)(fp + (size_t)grow * DD + kA + c);
                float4 f1 = *(const float4*)(fp + (size_t)grow * DD + kA + c + 4);
                av[j].x = pack2bf(f0.x, f0.y);
                av[j].y = pack2bf(f0.z, f0.w);
                av[j].z = pack2bf(f1.x, f1.y);
                av[j].w = pack2bf(f1.z, f1.w);
            } else {
                const ushort_t* sp = second ? Bm : (const ushort_t*)Av;
                av[j] = *(const uint4*)(sp + (size_t)grow * DD + kA + c);
            }
            wv[j] = *(const uint4*)(W + (size_t)r * KTOT + kW + c);
        }
        if (ch) __syncthreads();
#pragma unroll
        for (int j = 0; j < 2; ++j) {
            int g = tid + 256 * j;
            int r = g >> 2;
            int c = (g & 3) * 8;
            *(uint4*)(&At[r * 40 + c]) = av[j];
            *(uint4*)(&Wt[r * 40 + c]) = wv[j];
        }
        __syncthreads();

        bf16x8 af[4], bfr[4];
#pragma unroll
        for (int i = 0; i < 4; ++i)
            af[i] = *(const bf16x8*)(&At[(m0 + i * 16 + cl) * 40 + q * 8]);
#pragma unroll
        for (int j = 0; j < 4; ++j)
            bfr[j] = *(const bf16x8*)(&Wt[(n0 + j * 16 + cl) * 40 + q * 8]);
#pragma unroll
        for (int i = 0; i < 4; ++i)
#pragma unroll
            for (int j = 0; j < 4; ++j)
                acc[i][j] = __builtin_amdgcn_mfma_f32_16x16x32_bf16(
                    af[i], bfr[j], acc[i][j], 0, 0, 0);
    }

    // Epilogue. C/D layout: col=lane&15, row=(lane>>4)*4+reg  [m89/m91]
    __syncthreads();   // all waves done reading At/Wt before Ot overwrites
#pragma unroll
    for (int j = 0; j < 4; ++j) {
        int c = n0 + j * 16 + cl;
        float bv = bias[c];
#pragma unroll
        for (int i = 0; i < 4; ++i) {
#pragma unroll
            for (int reg = 0; reg < 4; ++reg) {
                int r = m0 + i * 16 + 4 * q + reg;
                float v = acc[i][j][reg] + bv;
                if constexpr (RELU) v = fmaxf(v, 0.f);
                Ot[r * 128 + c] = f2bf(v);
            }
        }
    }
    __syncthreads();
    int rows = NN - row0; if (rows > 128) rows = 128;
    for (int t = tid; t < rows * 16; t += 256) {
        int r = t >> 4, c8 = (t & 15) * 8;
        *(uint4*)(outp + (size_t)(row0 + r) * DD + c8) =
            *(const uint4*)(&Ot[r * 128 + c8]);
    }
}

// ---------------------------------------------------------------------------
// partA2: bin BOTH edge lists into 512-node buckets in one launch.
// Pair = (local_dst<<17) | src.  Blocks [0,196)->list 0, [196,392)->list 1.
// ---------------------------------------------------------------------------
__global__ __launch_bounds__(256) void partA2(
    const int* __restrict__ e0s, const int* __restrict__ e0d, int E0,
    const int* __restrict__ e1s, const int* __restrict__ e1d, int E1,
    int* __restrict__ bcnt, uint_t* __restrict__ pairs)
{
    __shared__ int hist[NB];
    __shared__ int base[NB];
    const int tid  = threadIdx.x;
    const int half = blockIdx.x >= PA_BLOCKS;
    const int* __restrict__ src = half ? e1s : e0s;
    const int* __restrict__ dst = half ? e1d : e0d;
    const int E = half ? E1 : E0;
    int* bc = bcnt + half * NB;
    uint_t* pp = pairs + (size_t)half * NB * CAPB;
    const int blk = blockIdx.x - half * PA_BLOCKS;
    const int chunk = (E + PA_BLOCKS - 1) / PA_BLOCKS;
    const int ea = blk * chunk;
    int eb = ea + chunk; if (eb > E) eb = E;

    for (int b = tid; b < NB; b += 256) hist[b] = 0;
    __syncthreads();
    for (int e = ea + tid; e < eb; e += 256)
        atomicAdd(&hist[dst[e] >> 9], 1);
    __syncthreads();
    for (int b = tid; b < NB; b += 256) {
        base[b] = atomicAdd(&bc[b], hist[b]);
        hist[b] = 0;
    }
    __syncthreads();
    for (int e = ea + tid; e < eb; e += 256) {
        int d = dst[e];
        int b = d >> 9;
        int off = atomicAdd(&hist[b], 1);
        int p = base[b] + off;
        if (p < CAPB)
            pp[(size_t)b * CAPB + p] =
                ((uint_t)(d & (NPB - 1)) << 17) | (uint_t)src[e];
    }
}

// ---------------------------------------------------------------------------
// partB: one block per bucket (both lists, 392 blocks). Sort the bucket's
// pairs by local dst in LDS, write the src list back IN PLACE into the
// pairs buffer (coalesced), emit counts[] and offs[].
// ---------------------------------------------------------------------------
__global__ __launch_bounds__(256, 2) void partB(
    uint_t* __restrict__ pairs, const int* __restrict__ bcnt,
    int* __restrict__ counts, int* __restrict__ offs)
{
    __shared__ int cnt[NPB];
    __shared__ int loff[NPB];
    __shared__ int ssc[256];
    __shared__ int image[CAPB];

    const int tid  = threadIdx.x;
    const int half = blockIdx.x >= NB;
    const int b    = blockIdx.x - half * NB;
    const int n0   = b << 9;
    int nb = NN - n0; if (nb > NPB) nb = NPB;
    int tot = bcnt[half * NB + b]; if (tot > CAPB) tot = CAPB;
    uint_t* pb = pairs + (size_t)(half * NB + b) * CAPB;
    const int gbase = (half * NB + b) * CAPB;
    int* cnts  = counts + (size_t)half * NN;
    int* offsl = offs   + (size_t)half * NN;

    for (int n = tid; n < NPB; n += 256) cnt[n] = 0;
    __syncthreads();
    for (int i = tid; i < tot; i += 256)
        atomicAdd(&cnt[pb[i] >> 17], 1);
    __syncthreads();

    // exclusive scan of cnt[0..511] with 256 threads
    int a0 = cnt[2 * tid], a1 = cnt[2 * tid + 1];
    int s = a0 + a1;
    ssc[tid] = s;
    __syncthreads();
    for (int off = 1; off < 256; off <<= 1) {
        int t = 0;
        if (tid >= off) t = ssc[tid - off];
        __syncthreads();
        if (tid >= off) ssc[tid] += t;
        __syncthreads();
    }
    int pre = ssc[tid] - s;
    loff[2 * tid]     = pre;
    loff[2 * tid + 1] = pre + a0;
    __syncthreads();

    for (int n = tid; n < nb; n += 256) {
        cnts[n0 + n]  = cnt[n];
        offsl[n0 + n] = gbase + loff[n];
    }
    for (int n = tid; n < NPB; n += 256) cnt[n] = 0;   // reuse as cursor
    __syncthreads();

    for (int i = tid; i < tot; i += 256) {
        uint_t p = pb[i];
        int ln  = p >> 17;
        int pos = loff[ln] + atomicAdd(&cnt[ln], 1);
        image[pos] = (int)(p & 0x1FFFFu);
    }
    __syncthreads();
    for (int i = tid; i < tot; i += 256) pb[i] = (uint_t)image[i];
}

// ---------------------------------------------------------------------------
// CSR mean-aggregate over bf16 h (register accumulation, no atomics).
// 16 lanes/node, uint4 (16 B)/lane, 8-deep unrolled gathers — 128 B/lane
// outstanding (2x R8) to push the per-CU load-throughput ceiling.
// ---------------------------------------------------------------------------
__global__ __launch_bounds__(256) void aggregate_bf16(
    const ushort_t* __restrict__ h, const uint_t* __restrict__ csr,
    const int* __restrict__ offs, const int* __restrict__ counts,
    ushort_t* __restrict__ mean, int nn)
{
    int gid  = blockIdx.x * 256 + threadIdx.x;
    int node = gid >> 4;
    if (node >= nn) return;
    int lane  = gid & 15;
    int start = offs[node];
    int cnt   = counts[node];

    float a0 = 0.f, a1 = 0.f, a2 = 0.f, a3 = 0.f;
    float a4 = 0.f, a5 = 0.f, a6 = 0.f, a7 = 0.f;
    int j = 0;
    for (; j + 8 <= cnt; j += 8) {
        int s[8];
#pragma unroll
        for (int u = 0; u < 8; ++u) s[u] = (int)csr[start + j + u];
        uint4 v[8];
#pragma unroll
        for (int u = 0; u < 8; ++u)
            v[u] = *(const uint4*)(h + (size_t)s[u] * DD + lane * 8);
#pragma unroll
        for (int u = 0; u < 8; ++u) {
            a0 += bflo(v[u].x); a1 += bfhi(v[u].x);
            a2 += bflo(v[u].y); a3 += bfhi(v[u].y);
            a4 += bflo(v[u].z); a5 += bfhi(v[u].z);
            a6 += bflo(v[u].w); a7 += bfhi(v[u].w);
        }
    }
    for (; j < cnt; ++j) {
        int s = (int)csr[start + j];
        uint4 v = *(const uint4*)(h + (size_t)s * DD + lane * 8);
        a0 += bflo(v.x); a1 += bfhi(v.x);
        a2 += bflo(v.y); a3 += bfhi(v.y);
        a4 += bflo(v.z); a5 += bfhi(v.z);
        a6 += bflo(v.w); a7 += bfhi(v.w);
    }
    float rinv = 1.0f / (float)(cnt > 1 ? cnt : 1);
    uint4 o;
    o.x = pack2bf(a0 * rinv, a1 * rinv);
    o.y = pack2bf(a2 * rinv, a3 * rinv);
    o.z = pack2bf(a4 * rinv, a5 * rinv);
    o.w = pack2bf(a6 * rinv, a7 * rinv);
    *(uint4*)(mean + (size_t)node * DD + lane * 8) = o;
}

// ---------------------------------------------------------------------------
// Fused edge scoring on bf16 h3: 16 lanes/edge, uint4 (16 B) loads.
// ---------------------------------------------------------------------------
__global__ __launch_bounds__(256) void score_both(
    const ushort_t* __restrict__ h,
    const int* __restrict__ ps, const int* __restrict__ pd,
    const int* __restrict__ ns, const int* __restrict__ nd,
    float* __restrict__ out, int EP, int TE)
{
    int gid = blockIdx.x * 256 + threadIdx.x;
    int e = gid >> 4;
    if (e >= TE) return;
    int lane = gid & 15;
    int si, di;
    if (e < EP) { si = ps[e]; di = pd[e]; }
    else        { si = ns[e - EP]; di = nd[e - EP]; }
    uint4 a = *(const uint4*)(h + (size_t)si * DD + lane * 8);
    uint4 b = *(const uint4*)(h + (size_t)di * DD + lane * 8);
    float s = bflo(a.x) * bflo(b.x) + bfhi(a.x) * bfhi(b.x)
            + bflo(a.y) * bflo(b.y) + bfhi(a.y) * bfhi(b.y)
            + bflo(a.z) * bflo(b.z) + bfhi(a.z) * bfhi(b.z)
            + bflo(a.w) * bflo(b.w) + bfhi(a.w) * bfhi(b.w);
#pragma unroll
    for (int off = 8; off; off >>= 1) s += __shfl_down(s, off, 16);
    if (lane == 0) out[e] = s;
}

// ---------------------------------------------------------------------------

extern "C" void kernel_launch(void* const* d_in, const int* in_sizes, int n_in,
                              void* d_out, int out_size, void* d_ws, size_t ws_size,
                              hipStream_t stream)
{
    const float* feat    = (const float*)d_in[0];
    const int*   e0s     = (const int*)d_in[1];
    const int*   e0d     = (const int*)d_in[2];
    const int*   e1s     = (const int*)d_in[3];
    const int*   e1d     = (const int*)d_in[4];
    const int*   ps      = (const int*)d_in[5];
    const int*   pd      = (const int*)d_in[6];
    const int*   ns      = (const int*)d_in[7];
    const int*   nd      = (const int*)d_in[8];
    const float* w_proj  = (const float*)d_in[9];
    const float* b_proj  = (const float*)d_in[10];
    const float* w_self1 = (const float*)d_in[11];
    const float* w_neigh1= (const float*)d_in[12];
    const float* b1      = (const float*)d_in[13];
    const float* w_self2 = (const float*)d_in[14];
    const float* w_neigh2= (const float*)d_in[15];
    const float* b2      = (const float*)d_in[16];

    float* out = (float*)d_out;

    const size_t NF = (size_t)NN * DD;
    char* base = (char*)d_ws;

    // bf16 buffers, NF*2 bytes each.
    ushort_t* h3   = (ushort_t*)base;
    ushort_t* h1   = (ushort_t*)(base + NF * 2);
    ushort_t* mean = (ushort_t*)(base + NF * 4);
    ushort_t* h2   = (ushort_t*)(base + NF * 6);

    uint_t* pairs  = (uint_t*)(base + NF * 8);           // 2*NB*CAPB*4 = 19.3 MB
    int*    bcnt   = (int*)(pairs + (size_t)2 * NB * CAPB);   // [2*NB]
    int*    counts = bcnt + 2 * NB;                      // [2*NN]
    int*    offs   = counts + 2 * NN;                    // [2*NN]
    ushort_t* wts  = (ushort_t*)(offs + 2 * NN);
    ushort_t* wtp = wts;                 // [128][128]
    ushort_t* wt1 = wts + 128 * 128;     // [128][256]
    ushort_t* wt2 = wt1 + 128 * 256;     // [128][256]

    const int E0 = in_sizes[1];
    const int E1 = in_sizes[3];
    const int EP = in_sizes[5];
    const int EN = in_sizes[7];

    const int GB  = (NN + 127) / 128;    // 782
    const int AGB = (NN * 16 + 255) / 256;

    // ---- Prep: weight transposes + bcnt zero (one small launch)
    prep<<<PREP_W_BLOCKS + PREP_Z_BLOCKS, 256, 0, stream>>>(
        w_proj, w_self1, w_neigh1, w_self2, w_neigh2, wtp, wt1, wt2, bcnt);

    // ---- Build both CSRs up front
    partA2<<<2 * PA_BLOCKS, 256, 0, stream>>>(
        e0s, e0d, E0, e1s, e1d, E1, bcnt, pairs);
    partB<<<2 * NB, 256, 0, stream>>>(pairs, bcnt, counts, offs);

    // ---- Layer 0: h1 = relu(feat @ w_proj + b_proj), fp32->bf16 fused
    gemm_bf16<true, false, true><<<GB, 256, 0, stream>>>(
        feat, nullptr, wtp, b_proj, h1);

    // ---- Layer 1: mean over edge0, then dual GEMM
    aggregate_bf16<<<AGB, 256, 0, stream>>>(h1, pairs, offs, counts, mean, NN);
    gemm_bf16<true, true, false><<<GB, 256, 0, stream>>>(
        h1, mean, wt1, b1, h2);

    // ---- Layer 2: mean over edge1, then dual GEMM
    aggregate_bf16<<<AGB, 256, 0, stream>>>(
        h2, pairs, offs + NN, counts + NN, mean, NN);
    gemm_bf16<false, true, false><<<GB, 256, 0, stream>>>(
        h2, mean, wt2, b2, h3);

    // ---- Fused scoring on bf16 h3
    const int TE = EP + EN;
    score_both<<<(TE * 16 + 255) / 256, 256, 0, stream>>>(
        h3, ps, pd, ns, nd, out, EP, TE);
}